// Round 3
// baseline (286.532 us; speedup 1.0000x reference)
//
#include <hip/hip_runtime.h>

#define NCLS 19
#define NPIX 65536          // 4*128*128
#define HW   16384          // 128*128
#define CHW  4194304        // 256*16384
#define LBL_BHW 262144      // 512*512
#define MAXS 4096
#define TEMP_INV (1.0f/0.07f)
#define EPS 1e-12f

// ---------------- K1: per-class sums of normalized f_t + counts ----------------
__global__ __launch_bounds__(256) void k1_class_sums(
    const float* __restrict__ ft, const int* __restrict__ tpl,
    float* __restrict__ g_sums, float* __restrict__ g_counts) {
  __shared__ float s_sums[NCLS * 256];
  __shared__ float s_counts[NCLS];
  int t = threadIdx.x;
  for (int i = t; i < NCLS * 256; i += 256) s_sums[i] = 0.f;
  if (t < NCLS) s_counts[t] = 0.f;
  __syncthreads();

  int n = blockIdx.x * 256 + t;
  int b = n >> 14;
  int hw = n & (HW - 1);
  int h = hw >> 7, w = hw & 127;
  int lbl = tpl[b * LBL_BHW + h * 2048 + w * 4];   // nearest-down: (4h, 4w)
  int seg = (lbl == 255) ? NCLS : lbl;

  size_t base = (size_t)b * CHW + hw;
  float ss = 0.f;
  #pragma unroll 8
  for (int c = 0; c < 256; ++c) {
    float v = ft[base + (size_t)c * HW];
    ss += v * v;
  }
  float rinv = 1.f / fmaxf(sqrtf(ss), EPS);

  if (seg < NCLS) {
    atomicAdd(&s_counts[seg], 1.f);
    int so = seg * 256;
    #pragma unroll 8
    for (int c = 0; c < 256; ++c) {
      float v = ft[base + (size_t)c * HW] * rinv;
      atomicAdd(&s_sums[so + c], v);
    }
  }
  __syncthreads();
  for (int i = t; i < NCLS * 256; i += 256) {
    float v = s_sums[i];
    if (v != 0.f) atomicAdd(&g_sums[i], v);
  }
  if (t < NCLS) {
    float v = s_counts[t];
    if (v != 0.f) atomicAdd(&g_counts[t], v);
  }
}

// ---------------- K2: normalize centroids ----------------
__global__ __launch_bounds__(256) void k2_centroids(
    const float* __restrict__ g_sums, const float* __restrict__ g_counts,
    float* __restrict__ g_cent) {
  int k = blockIdx.x;
  int c = threadIdx.x;
  float cnt = g_counts[k];
  float m = g_sums[k * 256 + c] / fmaxf(cnt, 1.f);
  float ss = m * m;
  #pragma unroll
  for (int off = 32; off; off >>= 1) ss += __shfl_down(ss, off, 64);
  __shared__ float s[4];
  int lane = c & 63, wv = c >> 6;
  if (lane == 0) s[wv] = ss;
  __syncthreads();
  float tot = s[0] + s[1] + s[2] + s[3];
  float rinv = 1.f / fmaxf(sqrtf(tot), EPS);
  g_cent[k * 256 + c] = m * rinv;
}

// ---------------- K3a: per-block valid counts ----------------
__global__ __launch_bounds__(256) void k3a_count(
    const int* __restrict__ sgt, const float* __restrict__ g_counts,
    int* __restrict__ blockCounts) {
  int t = threadIdx.x;
  int n = blockIdx.x * 256 + t;
  int b = n >> 14;
  int hw = n & (HW - 1);
  int h = hw >> 7, w = hw & 127;
  int lbl = sgt[b * LBL_BHW + h * 2048 + w * 4];
  int lc = min(max(lbl, 0), NCLS - 1);
  bool valid = (lbl != 255) && (g_counts[lc] > 0.f);
  unsigned long long m = __ballot(valid);
  __shared__ int s[4];
  int lane = t & 63, wv = t >> 6;
  if (lane == 0) s[wv] = __popcll(m);
  __syncthreads();
  if (t == 0) blockCounts[blockIdx.x] = s[0] + s[1] + s[2] + s[3];
}

// ---------------- K3b: exclusive scan of 256 block counts ----------------
__global__ __launch_bounds__(256) void k3b_scan(
    const int* __restrict__ blockCounts, int* __restrict__ blockPrefix,
    int* __restrict__ totalValid) {
  __shared__ int s[256];
  int t = threadIdx.x;
  int own = blockCounts[t];
  s[t] = own;
  __syncthreads();
  for (int off = 1; off < 256; off <<= 1) {
    int v = (t >= off) ? s[t - off] : 0;
    __syncthreads();
    s[t] += v;
    __syncthreads();
  }
  blockPrefix[t] = s[t] - own;
  if (t == 255) *totalValid = s[255];
}

// ---------------- K3c: CE over first 4096 valid pixels ----------------
__global__ __launch_bounds__(256) void k3c_ce(
    const float* __restrict__ fa, const int* __restrict__ sgt,
    const float* __restrict__ g_counts, const float* __restrict__ g_cent,
    const int* __restrict__ blockPrefix, float* __restrict__ loss_sum) {
  __shared__ float sc[NCLS * 256];
  __shared__ float shc[NCLS];
  __shared__ int swv[4];
  __shared__ float sred[4];
  int t = threadIdx.x;
  for (int i = t; i < NCLS * 256; i += 256) sc[i] = g_cent[i];
  if (t < NCLS) shc[t] = g_counts[t];
  __syncthreads();

  int n = blockIdx.x * 256 + t;
  int b = n >> 14;
  int hw = n & (HW - 1);
  int h = hw >> 7, w = hw & 127;
  int lbl = sgt[b * LBL_BHW + h * 2048 + w * 4];
  int lc = min(max(lbl, 0), NCLS - 1);
  bool valid = (lbl != 255) && (shc[lc] > 0.f);

  unsigned long long m = __ballot(valid);
  int lane = t & 63, wv = t >> 6;
  int lanePre = __popcll(m & ((1ull << lane) - 1ull));
  if (lane == 0) swv[wv] = __popcll(m);
  __syncthreads();
  int wavePre = 0;
  for (int i = 0; i < wv; ++i) wavePre += swv[i];
  int rank = blockPrefix[blockIdx.x] + wavePre + lanePre;

  float ce = 0.f;
  if (valid && rank < MAXS) {
    size_t base = (size_t)b * CHW + hw;
    float ss = 0.f;
    float dot[NCLS];
    #pragma unroll
    for (int k = 0; k < NCLS; ++k) dot[k] = 0.f;
    for (int c4 = 0; c4 < 64; ++c4) {
      float v0 = fa[base + (size_t)(c4 * 4 + 0) * HW];
      float v1 = fa[base + (size_t)(c4 * 4 + 1) * HW];
      float v2 = fa[base + (size_t)(c4 * 4 + 2) * HW];
      float v3 = fa[base + (size_t)(c4 * 4 + 3) * HW];
      ss += v0 * v0 + v1 * v1 + v2 * v2 + v3 * v3;
      #pragma unroll
      for (int k = 0; k < NCLS; ++k) {
        const float4 cv = *reinterpret_cast<const float4*>(&sc[k * 256 + c4 * 4]);
        dot[k] += v0 * cv.x + v1 * cv.y + v2 * cv.z + v3 * cv.w;
      }
    }
    float rinv = 1.f / fmaxf(sqrtf(ss), EPS);
    float mx = -3.402823466e38f;
    #pragma unroll
    for (int k = 0; k < NCLS; ++k) {
      float sk = (shc[k] > 0.f) ? dot[k] * rinv * TEMP_INV : -1e9f;
      dot[k] = sk;
      mx = fmaxf(mx, sk);
    }
    float sum = 0.f;
    #pragma unroll
    for (int k = 0; k < NCLS; ++k) sum += expf(dot[k] - mx);
    float lse = mx + logf(sum);
    ce = lse - dot[lc];
  }

  #pragma unroll
  for (int off = 32; off; off >>= 1) ce += __shfl_down(ce, off, 64);
  if (lane == 0) sred[wv] = ce;
  __syncthreads();
  if (t == 0) atomicAdd(loss_sum, sred[0] + sred[1] + sred[2] + sred[3]);
}

// ---------------- K4: finalize ----------------
__global__ void k4_final(const float* __restrict__ loss_sum,
                         const int* __restrict__ totalValid,
                         float* __restrict__ out) {
  float v = fminf((float)(*totalValid), (float)MAXS);
  out[0] = *loss_sum / fmaxf(v, 1.f);
}

// workspace byte offsets
#define WS_SUMS    0                    // float[19*256]
#define WS_COUNTS  19456                // float[19]
#define WS_BCNT    19536                // int[256]
#define WS_BPRE    20560                // int[256]
#define WS_TOTAL   21584                // int[1]
#define WS_LOSS    21588                // float[1]
#define WS_CENT    21600                // float[19*256]
#define WS_END     41056

extern "C" void kernel_launch(void* const* d_in, const int* in_sizes, int n_in,
                              void* d_out, int out_size, void* d_ws, size_t ws_size,
                              hipStream_t stream) {
  const float* f_aug = (const float*)d_in[0];
  const float* f_t = (const float*)d_in[1];
  const int* source_gt = (const int*)d_in[2];
  const int* target_pseudo = (const int*)d_in[3];
  float* out = (float*)d_out;

  char* ws = (char*)d_ws;
  float* g_sums = (float*)(ws + WS_SUMS);
  float* g_counts = (float*)(ws + WS_COUNTS);
  int* blockCounts = (int*)(ws + WS_BCNT);
  int* blockPrefix = (int*)(ws + WS_BPRE);
  int* totalValid = (int*)(ws + WS_TOTAL);
  float* loss_sum = (float*)(ws + WS_LOSS);
  float* g_cent = (float*)(ws + WS_CENT);

  hipMemsetAsync(d_ws, 0, WS_END, stream);

  k1_class_sums<<<256, 256, 0, stream>>>(f_t, target_pseudo, g_sums, g_counts);
  k2_centroids<<<NCLS, 256, 0, stream>>>(g_sums, g_counts, g_cent);
  k3a_count<<<256, 256, 0, stream>>>(source_gt, g_counts, blockCounts);
  k3b_scan<<<1, 256, 0, stream>>>(blockCounts, blockPrefix, totalValid);
  k3c_ce<<<256, 256, 0, stream>>>(f_aug, source_gt, g_counts, g_cent,
                                  blockPrefix, loss_sum);
  k4_final<<<1, 1, 0, stream>>>(loss_sum, totalValid, out);
}

// Round 7
// 247.594 us; speedup vs baseline: 1.1573x; 1.1573x over previous
//
#include <hip/hip_runtime.h>

#define NCLS 19
#define NPIX 65536          // 4*128*128
#define HW   16384          // 128*128
#define CHW  4194304        // 256*16384
#define LBL_BHW 262144      // 512*512
#define MAXS 4096
#define TEMP_INV (1.0f/0.07f)
#define EPS 1e-12f
#define NPART 8             // partial flush buffers for k1

// ---------------- K1: per-class sums of normalized f_t + counts ----------------
// 1024 blocks x 256 threads. Block = 64 pixels. Thread (g,q): g=tid>>4 is one of
// 16 channel-groups (16 ch each), q=tid&15 is a float4 (4 pixels) along hw.
// Loads: 64 lanes x 16B = 1KB/instr, coalesced. Values held in regs across the
// normalize reduction -> f_t read exactly once from HBM.
__global__ __launch_bounds__(256) void k1_class_sums(
    const float4* __restrict__ ft4, const int* __restrict__ tpl,
    float* __restrict__ g_sumsP, float* __restrict__ g_cntP) {
  __shared__ float s_sums[NCLS * 257];   // stride 257: distinct banks per class
  __shared__ float s_cnt[NCLS];
  __shared__ float4 s_ssp[16][16];       // [g][q] partial sumsq
  __shared__ float s_rinv[64];
  __shared__ int s_seg[64];
  int t = threadIdx.x;
  for (int i = t; i < NCLS * 257; i += 256) s_sums[i] = 0.f;
  if (t < NCLS) s_cnt[t] = 0.f;
  if (t < 64) {
    int n = blockIdx.x * 64 + t;
    int b = n >> 14, hw = n & (HW - 1);
    int h = hw >> 7, w = hw & 127;
    int lbl = tpl[b * LBL_BHW + h * 2048 + w * 4];   // nearest-down (4h,4w)
    s_seg[t] = (lbl >= 0 && lbl < NCLS) ? lbl : -1;  // 255 & out-of-range -> ignore
  }
  __syncthreads();
  if (t < 64 && s_seg[t] >= 0) atomicAdd(&s_cnt[s_seg[t]], 1.f);

  int q = t & 15, g = t >> 4;
  int n0 = blockIdx.x * 64;
  int b = n0 >> 14, hw0 = n0 & (HW - 1);
  size_t base4 = (size_t)b * (CHW / 4) + (size_t)(hw0 >> 2) + q;

  float4 v[16];
  float4 ssv = make_float4(0.f, 0.f, 0.f, 0.f);
  #pragma unroll
  for (int i = 0; i < 16; ++i) {
    int c = g * 16 + i;
    v[i] = ft4[base4 + (size_t)c * (HW / 4)];
    ssv.x += v[i].x * v[i].x; ssv.y += v[i].y * v[i].y;
    ssv.z += v[i].z * v[i].z; ssv.w += v[i].w * v[i].w;
  }
  s_ssp[g][q] = ssv;
  __syncthreads();
  if (t < 64) {
    int qq = t >> 2, j = t & 3;
    float ss = 0.f;
    #pragma unroll
    for (int g2 = 0; g2 < 16; ++g2) {
      const float* f = (const float*)&s_ssp[g2][qq];
      ss += f[j];
    }
    s_rinv[t] = 1.f / fmaxf(sqrtf(ss), EPS);
  }
  __syncthreads();
  float r0 = s_rinv[q * 4 + 0], r1 = s_rinv[q * 4 + 1];
  float r2 = s_rinv[q * 4 + 2], r3 = s_rinv[q * 4 + 3];
  int e0 = s_seg[q * 4 + 0], e1 = s_seg[q * 4 + 1];
  int e2 = s_seg[q * 4 + 2], e3 = s_seg[q * 4 + 3];
  #pragma unroll
  for (int i = 0; i < 16; ++i) {
    int c = g * 16 + i;
    if (e0 >= 0) atomicAdd(&s_sums[e0 * 257 + c], v[i].x * r0);
    if (e1 >= 0) atomicAdd(&s_sums[e1 * 257 + c], v[i].y * r1);
    if (e2 >= 0) atomicAdd(&s_sums[e2 * 257 + c], v[i].z * r2);
    if (e3 >= 0) atomicAdd(&s_sums[e3 * 257 + c], v[i].w * r3);
  }
  __syncthreads();
  // flush to one of NPART partial buffers (contention / NPART)
  float* dstS = g_sumsP + (blockIdx.x & (NPART - 1)) * (NCLS * 256);
  for (int e = t; e < NCLS * 256; e += 256) {
    float x = s_sums[(e >> 8) * 257 + (e & 255)];
    if (x != 0.f) atomicAdd(&dstS[e], x);
  }
  if (t < NCLS) {
    float x = s_cnt[t];
    if (x != 0.f) atomicAdd(&g_cntP[(blockIdx.x & (NPART - 1)) * NCLS + t], x);
  }
}

// ---------------- K2: sum partials, normalize centroids ----------------
__global__ __launch_bounds__(256) void k2_centroids(
    const float* __restrict__ g_sumsP, const float* __restrict__ g_cntP,
    float* __restrict__ g_cent, float* __restrict__ g_counts) {
  int k = blockIdx.x;
  int c = threadIdx.x;
  float m = 0.f, cnt = 0.f;
  #pragma unroll
  for (int s = 0; s < NPART; ++s) m += g_sumsP[s * (NCLS * 256) + k * 256 + c];
  #pragma unroll
  for (int s = 0; s < NPART; ++s) cnt += g_cntP[s * NCLS + k];
  m = m / fmaxf(cnt, 1.f);
  float ss = m * m;
  #pragma unroll
  for (int off = 32; off; off >>= 1) ss += __shfl_down(ss, off, 64);
  __shared__ float s[4];
  int lane = c & 63, wv = c >> 6;
  if (lane == 0) s[wv] = ss;
  __syncthreads();
  float tot = s[0] + s[1] + s[2] + s[3];
  float rinv = 1.f / fmaxf(sqrtf(tot), EPS);
  g_cent[k * 256 + c] = m * rinv;
  if (c == 0) g_counts[k] = cnt;
}

// ---------------- K3a: per-block valid counts ----------------
__global__ __launch_bounds__(256) void k3a_count(
    const int* __restrict__ sgt, const float* __restrict__ g_counts,
    int* __restrict__ blockCounts) {
  __shared__ float s_hc[NCLS];
  int t = threadIdx.x;
  if (t < NCLS) s_hc[t] = g_counts[t];
  __syncthreads();
  int n = blockIdx.x * 256 + t;
  int b = n >> 14, hw = n & (HW - 1);
  int h = hw >> 7, w = hw & 127;
  int lbl = sgt[b * LBL_BHW + h * 2048 + w * 4];
  int lc = min(max(lbl, 0), NCLS - 1);
  bool valid = (lbl != 255) && (s_hc[lc] > 0.f);
  unsigned long long m = __ballot(valid);
  __shared__ int s[4];
  int lane = t & 63, wv = t >> 6;
  if (lane == 0) s[wv] = __popcll(m);
  __syncthreads();
  if (t == 0) blockCounts[blockIdx.x] = s[0] + s[1] + s[2] + s[3];
}

// ---------------- K3b: exclusive scan of 256 block counts ----------------
__global__ __launch_bounds__(256) void k3b_scan(
    const int* __restrict__ blockCounts, int* __restrict__ blockPrefix,
    int* __restrict__ totalValid) {
  __shared__ int s[256];
  int t = threadIdx.x;
  int own = blockCounts[t];
  s[t] = own;
  __syncthreads();
  for (int off = 1; off < 256; off <<= 1) {
    int v = (t >= off) ? s[t - off] : 0;
    __syncthreads();
    s[t] += v;
    __syncthreads();
  }
  blockPrefix[t] = s[t] - own;
  if (t == 255) *totalValid = s[255];
}

// ---------------- K3c: compact indices of first MAXS valid pixels ----------------
__global__ __launch_bounds__(256) void k3c_compact(
    const int* __restrict__ sgt, const float* __restrict__ g_counts,
    const int* __restrict__ blockPrefix, int* __restrict__ sel) {
  __shared__ float s_hc[NCLS];
  __shared__ int swv[4];
  int t = threadIdx.x;
  if (t < NCLS) s_hc[t] = g_counts[t];
  __syncthreads();
  int n = blockIdx.x * 256 + t;
  int b = n >> 14, hw = n & (HW - 1);
  int h = hw >> 7, w = hw & 127;
  int lbl = sgt[b * LBL_BHW + h * 2048 + w * 4];
  int lc = min(max(lbl, 0), NCLS - 1);
  bool valid = (lbl != 255) && (s_hc[lc] > 0.f);
  unsigned long long m = __ballot(valid);
  int lane = t & 63, wv = t >> 6;
  int lanePre = __popcll(m & ((1ull << lane) - 1ull));
  if (lane == 0) swv[wv] = __popcll(m);
  __syncthreads();
  int wavePre = 0;
  for (int i = 0; i < wv; ++i) wavePre += swv[i];
  int rank = blockPrefix[blockIdx.x] + wavePre + lanePre;
  if (valid && rank < MAXS) sel[rank] = n;
}

// ---------------- K3d: CE over selected pixels + finalize ----------------
// 256 blocks x 256 threads; block = 16 selected pixels x 16 channel-groups.
__global__ __launch_bounds__(256) void k3d_ce(
    const float* __restrict__ fa, const int* __restrict__ sgt,
    const float* __restrict__ g_counts, const float* __restrict__ g_cent,
    const int* __restrict__ sel, const int* __restrict__ totalValid,
    float* __restrict__ loss_sum, int* __restrict__ done,
    float* __restrict__ out) {
  __shared__ float s_cent[NCLS * 256];
  __shared__ float s_hc[NCLS];
  __shared__ float s_red[16 * 21];   // [pixel][class(19), ss(19th slot=19)]
  __shared__ int s_n[16];
  __shared__ int s_lb[16];
  int t = threadIdx.x;
  for (int i = t; i < NCLS * 64; i += 256)
    ((float4*)s_cent)[i] = ((const float4*)g_cent)[i];
  if (t < NCLS) s_hc[t] = g_counts[t];
  for (int i = t; i < 16 * 21; i += 256) s_red[i] = 0.f;
  int nsel = min(*totalValid, MAXS);
  if (t < 16) {
    int mi = blockIdx.x * 16 + t;
    int n = (mi < nsel) ? sel[mi] : 0;
    s_n[t] = n;
    int b = n >> 14, hw = n & (HW - 1);
    int h = hw >> 7, w = hw & 127;
    int lbl = sgt[b * LBL_BHW + h * 2048 + w * 4];
    s_lb[t] = min(max(lbl, 0), NCLS - 1);
  }
  __syncthreads();

  int p = t & 15, g = t >> 4;
  int n = s_n[p];
  int b = n >> 14, hw = n & (HW - 1);
  size_t base = (size_t)b * CHW + hw;
  float dot[NCLS];
  #pragma unroll
  for (int k = 0; k < NCLS; ++k) dot[k] = 0.f;
  float ss = 0.f;
  #pragma unroll
  for (int i = 0; i < 16; ++i) {
    int c = g * 16 + i;
    float v = fa[base + (size_t)c * HW];
    ss += v * v;
    #pragma unroll
    for (int k = 0; k < NCLS; ++k) dot[k] += v * s_cent[k * 256 + c];
  }
  #pragma unroll
  for (int k = 0; k < NCLS; ++k) atomicAdd(&s_red[p * 21 + k], dot[k]);
  atomicAdd(&s_red[p * 21 + 19], ss);
  __syncthreads();

  float ce = 0.f;
  if (t < 16) {
    int mi = blockIdx.x * 16 + t;
    if (mi < nsel) {
      float rinv = 1.f / fmaxf(sqrtf(s_red[t * 21 + 19]), EPS);
      float mx = -3.402823466e38f;
      float sim[NCLS];
      #pragma unroll
      for (int k = 0; k < NCLS; ++k) {
        float sk = (s_hc[k] > 0.f) ? s_red[t * 21 + k] * rinv * TEMP_INV : -1e9f;
        sim[k] = sk;
        mx = fmaxf(mx, sk);
      }
      float sum = 0.f;
      #pragma unroll
      for (int k = 0; k < NCLS; ++k) sum += expf(sim[k] - mx);
      ce = mx + logf(sum) - sim[s_lb[t]];
    }
  }
  // wave-0 reduce (lanes >=16 carry 0)
  #pragma unroll
  for (int off = 32; off; off >>= 1) ce += __shfl_down(ce, off, 64);
  if (t == 0) {
    atomicAdd(loss_sum, ce);
    __threadfence();
    int old = atomicAdd(done, 1);
    if (old == (int)gridDim.x - 1) {
      float tl = atomicAdd(loss_sum, 0.f);  // coherent read
      out[0] = tl / fmaxf((float)nsel, 1.f);
    }
  }
}

// workspace byte offsets (all 256-aligned)
#define WS_SUMSP   0                        // float[NPART][19*256] = 155648 B
#define WS_CNTP    155648                   // float[NPART][19]     = 608 B
#define WS_COUNTS  156416                   // float[19]
#define WS_CENT    156672                   // float[19*256] = 19456 B
#define WS_BCNT    176128                   // int[256]
#define WS_BPRE    177152                   // int[256]
#define WS_TOTAL   178176                   // int[1]
#define WS_LOSS    178180                   // float[1]
#define WS_DONE    178184                   // int[1]
#define WS_SEL     178432                   // int[4096] = 16384 B
#define WS_END     194816

extern "C" void kernel_launch(void* const* d_in, const int* in_sizes, int n_in,
                              void* d_out, int out_size, void* d_ws, size_t ws_size,
                              hipStream_t stream) {
  const float* f_aug = (const float*)d_in[0];
  const float* f_t = (const float*)d_in[1];
  const int* source_gt = (const int*)d_in[2];
  const int* target_pseudo = (const int*)d_in[3];
  float* out = (float*)d_out;

  char* ws = (char*)d_ws;
  float* g_sumsP = (float*)(ws + WS_SUMSP);
  float* g_cntP = (float*)(ws + WS_CNTP);
  float* g_counts = (float*)(ws + WS_COUNTS);
  float* g_cent = (float*)(ws + WS_CENT);
  int* blockCounts = (int*)(ws + WS_BCNT);
  int* blockPrefix = (int*)(ws + WS_BPRE);
  int* totalValid = (int*)(ws + WS_TOTAL);
  float* loss_sum = (float*)(ws + WS_LOSS);
  int* done = (int*)(ws + WS_DONE);
  int* sel = (int*)(ws + WS_SEL);

  hipMemsetAsync(d_ws, 0, WS_END, stream);

  k1_class_sums<<<1024, 256, 0, stream>>>((const float4*)f_t, target_pseudo,
                                          g_sumsP, g_cntP);
  k2_centroids<<<NCLS, 256, 0, stream>>>(g_sumsP, g_cntP, g_cent, g_counts);
  k3a_count<<<256, 256, 0, stream>>>(source_gt, g_counts, blockCounts);
  k3b_scan<<<1, 256, 0, stream>>>(blockCounts, blockPrefix, totalValid);
  k3c_compact<<<256, 256, 0, stream>>>(source_gt, g_counts, blockPrefix, sel);
  k3d_ce<<<256, 256, 0, stream>>>(f_aug, source_gt, g_counts, g_cent, sel,
                                  totalValid, loss_sum, done, out);
}